// Round 7
// baseline (289.144 us; speedup 1.0000x reference)
//
#include <hip/hip_runtime.h>

typedef short sh8 __attribute__((ext_vector_type(8)));
typedef short sh4 __attribute__((ext_vector_type(4)));
typedef float f32x4 __attribute__((ext_vector_type(4)));

__device__ __forceinline__ short f2bf(float f) {
  unsigned u = __builtin_bit_cast(unsigned, f);
  u += 0x7fffu + ((u >> 16) & 1u);
  return (short)(u >> 16);
}

// fast 2^x: hardware v_exp_f32 via proper intrinsic (hazard-safe).
// Host pass may not see the builtin -> fall back to exp2f (never executed on host).
#if __has_builtin(__builtin_amdgcn_exp2f)
#define EXP2F(x) __builtin_amdgcn_exp2f(x)
#else
#define EXP2F(x) exp2f(x)
#endif

// pack two f32 -> two bf16 (truncate), unambiguous bit ops (compiler may fuse
// to v_perm). low short = bf16(a), high short = bf16(b).
__device__ __forceinline__ int pack_bf2(float a, float b) {
  unsigned ua = __builtin_bit_cast(unsigned, a);
  unsigned ub = __builtin_bit_cast(unsigned, b);
  return (int)((ub & 0xffff0000u) | (ua >> 16));
}

// ---------------- cast kernels ----------------
__global__ void cast_f32_bf16(const float* __restrict__ in, short* __restrict__ out, int n) {
  int i = (blockIdx.x * blockDim.x + threadIdx.x) * 4;
  if (i >= n) return;
  float4 f = *(const float4*)(in + i);
  sh4 o;
  o.x = f2bf(f.x); o.y = f2bf(f.y); o.z = f2bf(f.z); o.w = f2bf(f.w);
  *(sh4*)(out + i) = o;
}

// in: [K, Nn] fp32 row-major -> out: [Nn, K] bf16 row-major
__global__ void transpose_cast(const float* __restrict__ in, short* __restrict__ out, int K, int Nn) {
  int idx = blockIdx.x * blockDim.x + threadIdx.x;
  if (idx >= K * Nn) return;
  int k = idx / Nn;
  int n = idx - k * Nn;
  out[(size_t)n * K + k] = f2bf(in[idx]);
}

// ---------------- generic GEMM (used for proj): C[M,Nn] = A @ Bt^T + bias ----
template <int OUTF32>
__global__ __launch_bounds__(256) void gemm_bt(
    const short* __restrict__ A, const short* __restrict__ Bt,
    const float* __restrict__ bias, void* __restrict__ Cv,
    int M, int Nn, int K) {
  __shared__ short As[128][40];
  __shared__ short Bs[128][40];
  const int t = threadIdx.x;
  const int wave = t >> 6, lane = t & 63, quad = lane >> 4, l15 = lane & 15;
  const int wm = (wave >> 1) * 64, wn = (wave & 1) * 64;
  const int row0 = blockIdx.y * 128, col0 = blockIdx.x * 128;
  const int sr = t >> 2;
  const int sc = (t & 3) * 8;
  f32x4 acc[4][4] = {};
  const short* Ap = A + (size_t)(row0 + sr) * K + sc;
  const short* Bp = Bt + (size_t)(col0 + sr) * K + sc;

  for (int k0 = 0; k0 < K; k0 += 32) {
    uint4 a0 = *(const uint4*)(Ap + k0);
    uint4 a1 = *(const uint4*)(Ap + (size_t)64 * K + k0);
    uint4 b0 = *(const uint4*)(Bp + k0);
    uint4 b1 = *(const uint4*)(Bp + (size_t)64 * K + k0);
    __syncthreads();
    *(uint4*)&As[sr][sc] = a0;
    *(uint4*)&As[sr + 64][sc] = a1;
    *(uint4*)&Bs[sr][sc] = b0;
    *(uint4*)&Bs[sr + 64][sc] = b1;
    __syncthreads();
    sh8 af[4], bfv[4];
#pragma unroll
    for (int i = 0; i < 4; i++) af[i] = *(const sh8*)&As[wm + i * 16 + l15][quad * 8];
#pragma unroll
    for (int j = 0; j < 4; j++) bfv[j] = *(const sh8*)&Bs[wn + j * 16 + l15][quad * 8];
#pragma unroll
    for (int i = 0; i < 4; i++)
#pragma unroll
      for (int j = 0; j < 4; j++)
        acc[i][j] = __builtin_amdgcn_mfma_f32_16x16x32_bf16(af[i], bfv[j], acc[i][j], 0, 0, 0);
  }

#pragma unroll
  for (int i = 0; i < 4; i++)
#pragma unroll
    for (int j = 0; j < 4; j++) {
      int r = row0 + wm + i * 16 + quad * 4;
      int c = col0 + wn + j * 16 + l15;
      float bv = bias[c];
#pragma unroll
      for (int e = 0; e < 4; e++) {
        float v = acc[i][j][e] + bv;
        if (OUTF32)
          ((float*)Cv)[(size_t)(r + e) * Nn + c] = v;
        else
          ((short*)Cv)[(size_t)(r + e) * Nn + c] = f2bf(v);
      }
    }
}

// ---------------- QKV GEMM with per-head scatter ----------------
// A: xb [8192,768], Bt: wqkvT [2304,768]. Writes Qh/Kh/Vh: [48][2048][64] bf16.
// Q gets *0.125*log2(e) folded in (so attention can use raw v_exp_f32).
__global__ __launch_bounds__(256) void gemm_qkv(
    const short* __restrict__ A, const short* __restrict__ Bt,
    const float* __restrict__ bias,
    short* __restrict__ Qh, short* __restrict__ Kh, short* __restrict__ Vh) {
  const int K = 768;
  __shared__ short As[128][40];
  __shared__ short Bs[128][40];
  const int t = threadIdx.x;
  const int wave = t >> 6, lane = t & 63, quad = lane >> 4, l15 = lane & 15;
  const int wm = (wave >> 1) * 64, wn = (wave & 1) * 64;
  const int row0 = blockIdx.y * 128, col0 = blockIdx.x * 128;
  const int sr = t >> 2;
  const int sc = (t & 3) * 8;
  f32x4 acc[4][4] = {};
  const short* Ap = A + (size_t)(row0 + sr) * K + sc;
  const short* Bp = Bt + (size_t)(col0 + sr) * K + sc;

  for (int k0 = 0; k0 < K; k0 += 32) {
    uint4 a0 = *(const uint4*)(Ap + k0);
    uint4 a1 = *(const uint4*)(Ap + (size_t)64 * K + k0);
    uint4 b0 = *(const uint4*)(Bp + k0);
    uint4 b1 = *(const uint4*)(Bp + (size_t)64 * K + k0);
    __syncthreads();
    *(uint4*)&As[sr][sc] = a0;
    *(uint4*)&As[sr + 64][sc] = a1;
    *(uint4*)&Bs[sr][sc] = b0;
    *(uint4*)&Bs[sr + 64][sc] = b1;
    __syncthreads();
    sh8 af[4], bfv[4];
#pragma unroll
    for (int i = 0; i < 4; i++) af[i] = *(const sh8*)&As[wm + i * 16 + l15][quad * 8];
#pragma unroll
    for (int j = 0; j < 4; j++) bfv[j] = *(const sh8*)&Bs[wn + j * 16 + l15][quad * 8];
#pragma unroll
    for (int i = 0; i < 4; i++)
#pragma unroll
      for (int j = 0; j < 4; j++)
        acc[i][j] = __builtin_amdgcn_mfma_f32_16x16x32_bf16(af[i], bfv[j], acc[i][j], 0, 0, 0);
  }

  // s uniform per block: 768 % 128 == 0
  const int s = col0 >= 1536 ? 2 : (col0 >= 768 ? 1 : 0);
  short* dst = s == 0 ? Qh : (s == 1 ? Kh : Vh);
  const float scl = (s == 0) ? 0.125f * 1.44269504088896f : 1.0f;

#pragma unroll
  for (int j = 0; j < 4; j++) {
    int c = col0 + wn + j * 16 + l15;
    int hd = c - s * 768;
    int h = hd >> 6;
    float bv = bias[c];
#pragma unroll
    for (int i = 0; i < 4; i++) {
      int rbase = row0 + wm + i * 16 + quad * 4;
#pragma unroll
      for (int e = 0; e < 4; e++) {
        int r = rbase + e;
        int b = r >> 11, n = r & 2047;
        float v = (acc[i][j][e] + bv) * scl;
        dst[(size_t)(b * 12 + h) * 131072 + n * 64 + (hd & 63)] = f2bf(v);
      }
    }
  }
}

// ---------------- V transpose + key-permute ----------------
// Vh [48][2048][64] -> VhTp [48][64][2048]; within each 32-key group key kk
// goes to pos = ((kk&12)<<1) + (kk&3) + ((kk&16)>>2) so two 16-key S^T tiles
// pack directly into one 16x16x32 A-fragment for PV.
__global__ __launch_bounds__(256) void transpose_v(const short* __restrict__ Vh,
                                                   short* __restrict__ VhT) {
  __shared__ short Tl[64][72];
  const int bid = blockIdx.x;
  const int bh = bid >> 5, nt = bid & 31;
  const size_t hb = (size_t)bh * 131072;
  const int t = threadIdx.x;
  const int r0 = t >> 3;
  const int c0 = (t & 7) * 8;
  const int pos = ((r0 & 12) << 1) + (r0 & 3) + ((r0 & 16) >> 2);
  sh8 a = *(const sh8*)&Vh[hb + (size_t)(nt * 64 + r0) * 64 + c0];
  sh8 b = *(const sh8*)&Vh[hb + (size_t)(nt * 64 + r0 + 32) * 64 + c0];
#pragma unroll
  for (int j = 0; j < 8; j++) Tl[c0 + j][pos] = a[j];
#pragma unroll
  for (int j = 0; j < 8; j++) Tl[c0 + j][pos + 32] = b[j];
  __syncthreads();
  uint4 w0 = *(const uint4*)&Tl[r0][c0];
  uint4 w1 = *(const uint4*)&Tl[r0 + 32][c0];
  *(uint4*)&VhT[hb + (size_t)r0 * 2048 + nt * 64 + c0] = w0;
  *(uint4*)&VhT[hb + (size_t)(r0 + 32) * 2048 + nt * 64 + c0] = w1;
}

// ---------------- flash attention v5b ----------------
// K-frags direct from L2 (no LDS); V double-buffered in LDS (one barrier/tile);
// exp = 1 v_exp_f32 (intrinsic); P packed via bit-ops (trunc); P stays in regs.
__global__ __launch_bounds__(256, 3) void attn5(const short* __restrict__ Qh,
                                                const short* __restrict__ Kh,
                                                const short* __restrict__ VhTp,
                                                short* __restrict__ outb) {
  const int bid = blockIdx.x;
  const int qb = bid / 48;          // 0..15
  const int bh = bid - qb * 48;     // 48 % 8 == 0: all qb of a bh on one XCD
  const int t = threadIdx.x;
  const int wave = t >> 6, lane = t & 63, quad = lane >> 4, l15 = lane & 15;
  const size_t hb = (size_t)bh * 131072;
  const int qbase = qb * 128 + wave * 32;

  __shared__ short Vt[2][64][72];   // [buf][d][key-pos] (permuted)

  // Q fragments (B-operand layout): 32 q-rows per wave
  sh8 qa[2][2];
#pragma unroll
  for (int qt = 0; qt < 2; qt++) {
    const short* qp = Qh + hb + (size_t)(qbase + qt * 16 + l15) * 64;
    qa[qt][0] = *(const sh8*)(qp + quad * 8);
    qa[qt][1] = *(const sh8*)(qp + 32 + quad * 8);
  }

  f32x4 o[2][4] = {};
  f32x4 ls[2] = {};

  const int r0 = t >> 3;            // 0..31
  const int c0 = (t & 7) * 8;       // 0..56
  const short* vbase = VhTp + hb + (size_t)r0 * 2048 + c0;
  const short* kfb = Kh + hb + (size_t)l15 * 64 + quad * 8;

  // prefetch first V tile
  sh8 va = *(const sh8*)vbase;
  sh8 vb_ = *(const sh8*)(vbase + (size_t)32 * 2048);

#pragma unroll 2
  for (int kt = 0; kt < 32; kt++) {
    const int key0 = kt * 64;
    // issue K-frag loads for this tile (L2-resident, XCD-local)
    sh8 kf[4][2];
#pragma unroll
    for (int tk = 0; tk < 4; tk++) {
      const short* kp = kfb + (size_t)(key0 + tk * 16) * 64;
      kf[tk][0] = *(const sh8*)kp;
      kf[tk][1] = *(const sh8*)(kp + 32);
    }
    short(*V)[72] = Vt[kt & 1];
    *(sh8*)&V[r0][c0] = va;
    *(sh8*)&V[r0 + 32][c0] = vb_;
    __syncthreads();
    // prefetch next V tile (consumed next iteration)
    if (kt < 31) {
      va = *(const sh8*)(vbase + key0 + 64);
      vb_ = *(const sh8*)(vbase + (size_t)32 * 2048 + key0 + 64);
    }

#pragma unroll
    for (int g = 0; g < 2; g++) {   // two 32-key groups
      int4 pf[2];
#pragma unroll
      for (int tt = 0; tt < 2; tt++) {
        const int tk = g * 2 + tt;
#pragma unroll
        for (int qt = 0; qt < 2; qt++) {
          f32x4 z = {};
          z = __builtin_amdgcn_mfma_f32_16x16x32_bf16(kf[tk][0], qa[qt][0], z, 0, 0, 0);
          z = __builtin_amdgcn_mfma_f32_16x16x32_bf16(kf[tk][1], qa[qt][1], z, 0, 0, 0);
          f32x4 e;
          e[0] = EXP2F(z[0]);
          e[1] = EXP2F(z[1]);
          e[2] = EXP2F(z[2]);
          e[3] = EXP2F(z[3]);
          ls[qt] += e;
          if (tt == 0) {
            pf[qt].x = pack_bf2(e[0], e[1]);
            pf[qt].y = pack_bf2(e[2], e[3]);
          } else {
            pf[qt].z = pack_bf2(e[0], e[1]);
            pf[qt].w = pack_bf2(e[2], e[3]);
          }
        }
      }
#pragma unroll
      for (int dt = 0; dt < 4; dt++) {
        sh8 vf = *(const sh8*)&V[dt * 16 + l15][g * 32 + quad * 8];
#pragma unroll
        for (int qt = 0; qt < 2; qt++)
          o[qt][dt] = __builtin_amdgcn_mfma_f32_16x16x32_bf16(
              __builtin_bit_cast(sh8, pf[qt]), vf, o[qt][dt], 0, 0, 0);
      }
    }
  }

  // reduce row-sums: horizontal 4, then across quads
  float lsum[2];
#pragma unroll
  for (int qt = 0; qt < 2; qt++) {
    float v = ls[qt][0] + ls[qt][1] + ls[qt][2] + ls[qt][3];
    v += __shfl_xor(v, 16, 64);
    v += __shfl_xor(v, 32, 64);
    lsum[qt] = v;
  }

  const int b = bh / 12, h = bh - b * 12;
#pragma unroll
  for (int qt = 0; qt < 2; qt++)
#pragma unroll
    for (int r = 0; r < 4; r++) {
      float L = __shfl(lsum[qt], quad * 4 + r, 64);
      float inv = 1.f / L;
      int n = qbase + qt * 16 + quad * 4 + r;
      short* op = outb + (size_t)(b * 2048 + n) * 768 + h * 64 + l15;
#pragma unroll
      for (int dt = 0; dt < 4; dt++) op[dt * 16] = f2bf(o[qt][dt][r] * inv);
    }
}

// ---------------- launcher ----------------
extern "C" void kernel_launch(void* const* d_in, const int* in_sizes, int n_in,
                              void* d_out, int out_size, void* d_ws, size_t ws_size,
                              hipStream_t stream) {
  const float* x = (const float*)d_in[0];
  const float* w_qkv = (const float*)d_in[1];
  const float* b_qkv = (const float*)d_in[2];
  const float* w_proj = (const float*)d_in[3];
  const float* b_proj = (const float*)d_in[4];
  float* out = (float*)d_out;

  char* p = (char*)d_ws;
  short* xb = (short*)p;     p += (size_t)8192 * 768 * 2;
  short* wqkvT = (short*)p;  p += (size_t)2304 * 768 * 2;
  short* wprojT = (short*)p; p += (size_t)768 * 768 * 2;
  short* Qh = (short*)p;     p += (size_t)48 * 131072 * 2;
  short* Kh = (short*)p;     p += (size_t)48 * 131072 * 2;
  short* Vh = (short*)p;     p += (size_t)48 * 131072 * 2;
  short* attnb = (short*)p;  p += (size_t)8192 * 768 * 2;
  short* VhTp = xb;  // alias: xb dead after gemm_qkv; VhTp written after

  cast_f32_bf16<<<(8192 * 768 / 4) / 256, 256, 0, stream>>>(x, xb, 8192 * 768);
  transpose_cast<<<(768 * 2304 + 255) / 256, 256, 0, stream>>>(w_qkv, wqkvT, 768, 2304);
  transpose_cast<<<(768 * 768 + 255) / 256, 256, 0, stream>>>(w_proj, wprojT, 768, 768);

  dim3 g1(2304 / 128, 8192 / 128);
  gemm_qkv<<<g1, 256, 0, stream>>>(xb, wqkvT, b_qkv, Qh, Kh, Vh);

  transpose_v<<<48 * 32, 256, 0, stream>>>(Vh, VhTp);

  attn5<<<16 * 48, 256, 0, stream>>>(Qh, Kh, VhTp, attnb);

  dim3 g2(768 / 128, 8192 / 128);
  gemm_bt<1><<<g2, 256, 0, stream>>>(attnb, wprojT, b_proj, out, 8192, 768, 768);
}